// Round 5
// baseline (290.895 us; speedup 1.0000x reference)
//
#include <hip/hip_runtime.h>
#include <hip/hip_bf16.h>

// Problem constants (reference: B,S,D,K = 4, 8192, 512, 20)
#define BB 4
#define SS 8192
#define DD 512
#define KK 20
#define GG 8                 // reduce groups
#define BKD (BB * KK * DD)   // 40960

__device__ __forceinline__ float dot4(float4 a, float4 b) {
  return a.x * b.x + a.y * b.y + a.z * b.z + a.w * b.w;
}

// ---------------------------------------------------------------------------
// k0: params[k]=||c_k||^2, params[K+k]=0.5/sigma^2, params[2K+k]=amp
// ---------------------------------------------------------------------------
__global__ void k0_params(const float* __restrict__ pos,
                          const float* __restrict__ log_scales,
                          const float* __restrict__ amps,
                          float* __restrict__ params) {
  int k = blockIdx.x;
  int lane = threadIdx.x;
  float acc = 0.f;
  for (int d = lane; d < DD; d += 64) { float p = pos[k * DD + d]; acc += p * p; }
#pragma unroll
  for (int off = 32; off > 0; off >>= 1) acc += __shfl_xor(acc, off);
  if (lane == 0) {
    params[k] = acc;
    float s = __expf(log_scales[k]);
    params[KK + k] = 0.5f / (s * s);
    params[2 * KK + k] = amps[k];
  }
}

// ---------------------------------------------------------------------------
// kA: attn. 512 blocks x 256 thr; 64 tokens/block; 16 lanes/token;
// 4 tokens/thread (q, q+16, q+32, q+48): each pos LDS b128 read feeds 4
// token-dots -> LDS-issue floor halved vs 2-token variant.
// ---------------------------------------------------------------------------
__global__ __launch_bounds__(256) void kA_attn(
    const float* __restrict__ x, const float* __restrict__ pos,
    const float* __restrict__ params, float* __restrict__ attn_g) {
  __shared__ float pos_s[KK * DD];   // 40 KB
  __shared__ float prm_s[3 * KK];
  int tid = threadIdx.x;
  for (int i = tid; i < KK * DD / 4; i += 256)
    ((float4*)pos_s)[i] = ((const float4*)pos)[i];
  if (tid < 3 * KK) prm_s[tid] = params[tid];
  __syncthreads();

  int b = blockIdx.x >> 7;           // 128 chunks/batch, 64 tokens each
  int c = blockIdx.x & 127;
  size_t row0 = (size_t)b * SS + (size_t)c * 64;
  int q = tid >> 4;                  // 0..15
  int dsub = tid & 15;

  const float* xq = x + (row0 + q) * DD;

  float acc[4][KK];
  float x2[4];
#pragma unroll
  for (int r = 0; r < 4; ++r) {
    x2[r] = 0.f;
#pragma unroll
    for (int k = 0; k < KK; ++k) acc[r][k] = 0.f;
  }

#pragma unroll 2
  for (int j = 0; j < 8; ++j) {
    int d0 = j * 64 + dsub * 4;
    float4 xv[4];
#pragma unroll
    for (int r = 0; r < 4; ++r) xv[r] = *(const float4*)(xq + (size_t)(r * 16) * DD + d0);
#pragma unroll
    for (int r = 0; r < 4; ++r) x2[r] += dot4(xv[r], xv[r]);
#pragma unroll
    for (int k = 0; k < KK; ++k) {
      float4 p = *(const float4*)(pos_s + k * DD + d0);
#pragma unroll
      for (int r = 0; r < 4; ++r) acc[r][k] += dot4(xv[r], p);
    }
  }

  // butterfly over 16 dsub lanes
#pragma unroll
  for (int r = 0; r < 4; ++r) {
#pragma unroll
    for (int m = 1; m <= 8; m <<= 1) x2[r] += __shfl_xor(x2[r], m);
#pragma unroll
    for (int k = 0; k < KK; ++k) {
#pragma unroll
      for (int m = 1; m <= 8; m <<= 1) acc[r][k] += __shfl_xor(acc[r][k], m);
    }
  }

  if (dsub == 0) {
#pragma unroll
    for (int r = 0; r < 4; ++r) {
      float gg[KK];
      float sum = 0.f;
#pragma unroll
      for (int k = 0; k < KK; ++k) {
        float d2 = fmaxf(x2[r] - 2.f * acc[r][k] + prm_s[k], 0.f);
        gg[k] = prm_s[2 * KK + k] * __expf(-prm_s[KK + k] * d2);
        sum += gg[k];
      }
      float inv = 1.f / (sum + 1e-8f);
      float* ar = attn_g + (row0 + q + r * 16) * KK;
#pragma unroll
      for (int k = 0; k < KK; ++k) ar[k] = gg[k] * inv;
    }
  }
}

// ---------------------------------------------------------------------------
// kB: Mpart[b,c,k,d] = sum_{s in chunk} attn[s,k]*x[s,d].
// grid (cpb, BB) x 256 thr; thread owns float2 d-slot; no LDS -> high occ.
// ---------------------------------------------------------------------------
__global__ __launch_bounds__(256) void kB_scatter(
    const float* __restrict__ x, const float* __restrict__ attn,
    float* __restrict__ Mpart, int tpc) {
  int t = threadIdx.x;
  int c = blockIdx.x;
  int b = blockIdx.y;
  int cpb = gridDim.x;
  size_t row0 = (size_t)b * SS + (size_t)c * tpc;

  float2 Ml[KK];
#pragma unroll
  for (int k = 0; k < KK; ++k) Ml[k] = make_float2(0.f, 0.f);

  const float* xb = x + row0 * DD + 2 * t;
  const float* ab = attn + row0 * KK;
  for (int s = 0; s < tpc; ++s) {
    float2 xv = *(const float2*)(xb + (size_t)s * DD);
    const float4* ar4 = (const float4*)(ab + s * KK);
#pragma unroll
    for (int kk = 0; kk < KK / 4; ++kk) {
      float4 a4 = ar4[kk];
      Ml[4 * kk + 0].x += a4.x * xv.x; Ml[4 * kk + 0].y += a4.x * xv.y;
      Ml[4 * kk + 1].x += a4.y * xv.x; Ml[4 * kk + 1].y += a4.y * xv.y;
      Ml[4 * kk + 2].x += a4.z * xv.x; Ml[4 * kk + 2].y += a4.z * xv.y;
      Ml[4 * kk + 3].x += a4.w * xv.x; Ml[4 * kk + 3].y += a4.w * xv.y;
    }
  }
  float* mp = Mpart + ((size_t)b * cpb + c) * KK * DD + 2 * t;
#pragma unroll
  for (int k = 0; k < KK; ++k) *(float2*)(mp + (size_t)k * DD) = Ml[k];
}

// ---------------------------------------------------------------------------
// kC1: parallel partial reduce Mpart -> red8[GG][B,K,D].
// 1280 blocks x 256 thr; thread sums cpg slabs, coalesced reads.
// ---------------------------------------------------------------------------
__global__ __launch_bounds__(256) void kC1_reduce(
    const float* __restrict__ Mpart, float* __restrict__ red8,
    int cpb, int cpg) {
  int idx = blockIdx.x * 256 + threadIdx.x;   // 0 .. GG*BKD-1
  int g = idx / BKD;
  int rem = idx - g * BKD;
  int b = rem / (KK * DD);
  int kd = rem - b * (KK * DD);
  const float* p = Mpart + ((size_t)b * cpb + (size_t)g * cpg) * KK * DD + kd;
  float acc = 0.f;
#pragma unroll 8
  for (int c = 0; c < cpg; ++c) acc += p[(size_t)c * KK * DD];
  red8[idx] = acc;
}

// ---------------------------------------------------------------------------
// k3f8: final reduce (GG values) + proj_v + proj_o. 80 blocks x 512 thr.
// ---------------------------------------------------------------------------
__global__ __launch_bounds__(512) void k3f8(
    const float* __restrict__ red8, const float* __restrict__ w_v,
    const float* __restrict__ w_o, float* __restrict__ ws2) {
  __shared__ float m_s[DD];
  __shared__ float v_s[DD];
  int bk = blockIdx.x;
  int e = threadIdx.x;

  const float* p = red8 + (size_t)bk * DD + e;   // red8[g][bk][e], g-stride BKD
  float acc = 0.f;
#pragma unroll
  for (int g = 0; g < GG; ++g) acc += p[(size_t)g * BKD];
  m_s[e] = acc;
  __syncthreads();

  const float4* wr = (const float4*)(w_v + (size_t)e * DD);
  float a2 = 0.f;
#pragma unroll 4
  for (int j = 0; j < DD / 4; ++j) a2 += dot4(((const float4*)m_s)[j], wr[j]);
  v_s[e] = a2;
  __syncthreads();

  const float4* wr2 = (const float4*)(w_o + (size_t)e * DD);
  float a3 = 0.f;
#pragma unroll 4
  for (int j = 0; j < DD / 4; ++j) a3 += dot4(((const float4*)v_s)[j], wr2[j]);
  ws2[(size_t)bk * DD + e] = a3;
}

// ---------------------------------------------------------------------------
// k5: out[b,s,:] = sum_k attn[b,s,k]*ws2[b,k,:]. 2048 blocks x 256 thr;
// thread owns float4 e-slot; 16B coalesced stores.
// ---------------------------------------------------------------------------
__global__ __launch_bounds__(256) void k5_gather(
    const float* __restrict__ attn, const float* __restrict__ ws2,
    float* __restrict__ out) {
  int tid = threadIdx.x;
  int b = blockIdx.x >> 9;           // 512 chunks per batch
  int sc = blockIdx.x & 511;
  size_t s0 = (size_t)sc * 16;
  int tr = tid >> 7;                 // 0/1: which of two token rows
  int e4 = tid & 127;                // float4 column slot

  float4 w[KK];
  const float* wb = ws2 + (size_t)b * KK * DD + e4 * 4;
#pragma unroll
  for (int k = 0; k < KK; ++k) w[k] = *(const float4*)(wb + (size_t)k * DD);

  size_t rowA = (size_t)b * SS + s0 + tr;
  const float* ar = attn + rowA * KK;
  float* orow = out + rowA * DD + e4 * 4;

#pragma unroll 2
  for (int i = 0; i < 8; ++i) {
    const float4* a4 = (const float4*)(ar + (size_t)2 * i * KK);
    float4 A = a4[0], Bv = a4[1], C = a4[2], Dv = a4[3], E = a4[4];
    float4 o = make_float4(0.f, 0.f, 0.f, 0.f);
#define ACC(av, kbase) \
    o.x += av * w[kbase].x; o.y += av * w[kbase].y; \
    o.z += av * w[kbase].z; o.w += av * w[kbase].w;
    ACC(A.x, 0)  ACC(A.y, 1)  ACC(A.z, 2)  ACC(A.w, 3)
    ACC(Bv.x, 4) ACC(Bv.y, 5) ACC(Bv.z, 6) ACC(Bv.w, 7)
    ACC(C.x, 8)  ACC(C.y, 9)  ACC(C.z, 10) ACC(C.w, 11)
    ACC(Dv.x, 12) ACC(Dv.y, 13) ACC(Dv.z, 14) ACC(Dv.w, 15)
    ACC(E.x, 16) ACC(E.y, 17) ACC(E.z, 18) ACC(E.w, 19)
#undef ACC
    *(float4*)(orow + (size_t)2 * i * DD) = o;
  }
}

// ---------------------------------------------------------------------------
extern "C" void kernel_launch(void* const* d_in, const int* in_sizes, int n_in,
                              void* d_out, int out_size, void* d_ws, size_t ws_size,
                              hipStream_t stream) {
  const float* x   = (const float*)d_in[0];
  const float* pos = (const float*)d_in[1];
  const float* ls  = (const float*)d_in[2];
  const float* am  = (const float*)d_in[3];
  const float* w_v = (const float*)d_in[4];
  const float* w_o = (const float*)d_in[5];
  float* out = (float*)d_out;

  float* ws     = (float*)d_ws;
  float* attn   = ws;                                 // B*S*K = 655360 f
  float* ws2    = attn + (size_t)BB * SS * KK;        // B*K*D = 40960 f
  float* params = ws2 + (size_t)BB * KK * DD;         // 64 f
  float* red8   = params + 64;                        // GG*BKD = 327680 f
  float* Mpart  = red8 + (size_t)GG * BKD;

  size_t head_f = (size_t)BB * SS * KK + (size_t)BB * KK * DD + 64 + (size_t)GG * BKD;
  int cpb = 256, tpc = 32;
  size_t need = (head_f + (size_t)BB * cpb * KK * DD) * sizeof(float);  // ~46.0 MB
  if (ws_size < need) { cpb = 128; tpc = 64; }                          // ~25.1 MB
  int cpg = cpb / GG;

  k0_params<<<KK, 64, 0, stream>>>(pos, ls, am, params);
  kA_attn<<<512, 256, 0, stream>>>(x, pos, params, attn);
  kB_scatter<<<dim3(cpb, BB), 256, 0, stream>>>(x, attn, Mpart, tpc);
  kC1_reduce<<<(GG * BKD) / 256, 256, 0, stream>>>(Mpart, red8, cpb, cpg);
  k3f8<<<BB * KK, 512, 0, stream>>>(red8, w_v, w_o, ws2);
  k5_gather<<<2048, 256, 0, stream>>>(attn, ws2, out);
}

// Round 6
// 256.864 us; speedup vs baseline: 1.1325x; 1.1325x over previous
//
#include <hip/hip_runtime.h>
#include <hip/hip_bf16.h>

// Problem constants (reference: B,S,D,K = 4, 8192, 512, 20)
#define BB 4
#define SS 8192
#define DD 512
#define KK 20
#define GG 8                 // reduce groups
#define BKD (BB * KK * DD)   // 40960

__device__ __forceinline__ float dot4(float4 a, float4 b) {
  return a.x * b.x + a.y * b.y + a.z * b.z + a.w * b.w;
}

// ---------------------------------------------------------------------------
// k0: params[k]=||c_k||^2, params[K+k]=0.5/sigma^2, params[2K+k]=amp
// ---------------------------------------------------------------------------
__global__ void k0_params(const float* __restrict__ pos,
                          const float* __restrict__ log_scales,
                          const float* __restrict__ amps,
                          float* __restrict__ params) {
  int k = blockIdx.x;
  int lane = threadIdx.x;
  float acc = 0.f;
  for (int d = lane; d < DD; d += 64) { float p = pos[k * DD + d]; acc += p * p; }
#pragma unroll
  for (int off = 32; off > 0; off >>= 1) acc += __shfl_xor(acc, off);
  if (lane == 0) {
    params[k] = acc;
    float s = __expf(log_scales[k]);
    params[KK + k] = 0.5f / (s * s);
    params[2 * KK + k] = amps[k];
  }
}

// ---------------------------------------------------------------------------
// kA: attn. 512 blocks x 256 thr; 64 tokens/block; 16 lanes/token;
// 4 tokens/thread (q, q+16, q+32, q+48): each pos LDS b128 read feeds 4 dots.
// ---------------------------------------------------------------------------
__global__ __launch_bounds__(256) void kA_attn(
    const float* __restrict__ x, const float* __restrict__ pos,
    const float* __restrict__ params, float* __restrict__ attn_g) {
  __shared__ float pos_s[KK * DD];   // 40 KB
  __shared__ float prm_s[3 * KK];
  int tid = threadIdx.x;
  for (int i = tid; i < KK * DD / 4; i += 256)
    ((float4*)pos_s)[i] = ((const float4*)pos)[i];
  if (tid < 3 * KK) prm_s[tid] = params[tid];
  __syncthreads();

  int b = blockIdx.x >> 7;           // 128 chunks/batch, 64 tokens each
  int c = blockIdx.x & 127;
  size_t row0 = (size_t)b * SS + (size_t)c * 64;
  int q = tid >> 4;                  // 0..15
  int dsub = tid & 15;

  const float* xq = x + (row0 + q) * DD;

  float acc[4][KK];
  float x2[4];
#pragma unroll
  for (int r = 0; r < 4; ++r) {
    x2[r] = 0.f;
#pragma unroll
    for (int k = 0; k < KK; ++k) acc[r][k] = 0.f;
  }

#pragma unroll 2
  for (int j = 0; j < 8; ++j) {
    int d0 = j * 64 + dsub * 4;
    float4 xv[4];
#pragma unroll
    for (int r = 0; r < 4; ++r) xv[r] = *(const float4*)(xq + (size_t)(r * 16) * DD + d0);
#pragma unroll
    for (int r = 0; r < 4; ++r) x2[r] += dot4(xv[r], xv[r]);
#pragma unroll
    for (int k = 0; k < KK; ++k) {
      float4 p = *(const float4*)(pos_s + k * DD + d0);
#pragma unroll
      for (int r = 0; r < 4; ++r) acc[r][k] += dot4(xv[r], p);
    }
  }

#pragma unroll
  for (int r = 0; r < 4; ++r) {
#pragma unroll
    for (int m = 1; m <= 8; m <<= 1) x2[r] += __shfl_xor(x2[r], m);
#pragma unroll
    for (int k = 0; k < KK; ++k) {
#pragma unroll
      for (int m = 1; m <= 8; m <<= 1) acc[r][k] += __shfl_xor(acc[r][k], m);
    }
  }

  if (dsub == 0) {
#pragma unroll
    for (int r = 0; r < 4; ++r) {
      float gg[KK];
      float sum = 0.f;
#pragma unroll
      for (int k = 0; k < KK; ++k) {
        float d2 = fmaxf(x2[r] - 2.f * acc[r][k] + prm_s[k], 0.f);
        gg[k] = prm_s[2 * KK + k] * __expf(-prm_s[KK + k] * d2);
        sum += gg[k];
      }
      float inv = 1.f / (sum + 1e-8f);
      float* ar = attn_g + (row0 + q + r * 16) * KK;
#pragma unroll
      for (int k = 0; k < KK; ++k) ar[k] = gg[k] * inv;
    }
  }
}

// ---------------------------------------------------------------------------
// kB: Mpart[b,c,k,d] = sum_{s in chunk} attn[s,k]*x[s,d].
// grid (cpb, BB) x 256 thr; thread owns float2 d-slot; no LDS -> high occ.
// ---------------------------------------------------------------------------
__global__ __launch_bounds__(256) void kB_scatter(
    const float* __restrict__ x, const float* __restrict__ attn,
    float* __restrict__ Mpart, int tpc) {
  int t = threadIdx.x;
  int c = blockIdx.x;
  int b = blockIdx.y;
  int cpb = gridDim.x;
  size_t row0 = (size_t)b * SS + (size_t)c * tpc;

  float2 Ml[KK];
#pragma unroll
  for (int k = 0; k < KK; ++k) Ml[k] = make_float2(0.f, 0.f);

  const float* xb = x + row0 * DD + 2 * t;
  const float* ab = attn + row0 * KK;
  for (int s = 0; s < tpc; ++s) {
    float2 xv = *(const float2*)(xb + (size_t)s * DD);
    const float4* ar4 = (const float4*)(ab + s * KK);
#pragma unroll
    for (int kk = 0; kk < KK / 4; ++kk) {
      float4 a4 = ar4[kk];
      Ml[4 * kk + 0].x += a4.x * xv.x; Ml[4 * kk + 0].y += a4.x * xv.y;
      Ml[4 * kk + 1].x += a4.y * xv.x; Ml[4 * kk + 1].y += a4.y * xv.y;
      Ml[4 * kk + 2].x += a4.z * xv.x; Ml[4 * kk + 2].y += a4.z * xv.y;
      Ml[4 * kk + 3].x += a4.w * xv.x; Ml[4 * kk + 3].y += a4.w * xv.y;
    }
  }
  float* mp = Mpart + ((size_t)b * cpb + c) * KK * DD + 2 * t;
#pragma unroll
  for (int k = 0; k < KK; ++k) *(float2*)(mp + (size_t)k * DD) = Ml[k];
}

// ---------------------------------------------------------------------------
// kC1: parallel partial reduce Mpart -> red8[GG][B,K,D]. Coalesced.
// ---------------------------------------------------------------------------
__global__ __launch_bounds__(256) void kC1_reduce(
    const float* __restrict__ Mpart, float* __restrict__ red8,
    int cpb, int cpg) {
  int idx = blockIdx.x * 256 + threadIdx.x;   // 0 .. GG*BKD-1
  int g = idx / BKD;
  int rem = idx - g * BKD;
  int b = rem / (KK * DD);
  int kd = rem - b * (KK * DD);
  const float* p = Mpart + ((size_t)b * cpb + (size_t)g * cpg) * KK * DD + kd;
  float acc = 0.f;
#pragma unroll 8
  for (int c = 0; c < cpg; ++c) acc += p[(size_t)c * KK * DD];
  red8[idx] = acc;
}

// ---------------------------------------------------------------------------
// kP: coalesced GEMV tile: out[bk][e] = sum_d in[bk][d] * W[e][d].
// grid (80, 8) x 256 thr. Wave-per-row: the 64 lanes read 64 CONSECUTIVE
// float4 of row W[e] (1KB contiguous per instr), dot vs LDS-staged m,
// 6-step shfl_xor reduce. mode 0: m = sum_g red8[g][bk][:]; mode 1: m = in[bk][:].
// ---------------------------------------------------------------------------
__global__ __launch_bounds__(256) void kP_gemv(
    const float* __restrict__ in, const float* __restrict__ W,
    float* __restrict__ out, int mode) {
  __shared__ float m_s[DD];
  int tid = threadIdx.x;
  int bk = blockIdx.x;
  int et = blockIdx.y;

  for (int i = tid; i < DD; i += 256) {
    float a;
    if (mode == 0) {
      const float* p = in + (size_t)bk * DD + i;   // red8[g][bk][:], g-stride BKD
      a = 0.f;
#pragma unroll
      for (int g = 0; g < GG; ++g) a += p[(size_t)g * BKD];
    } else {
      a = in[(size_t)bk * DD + i];
    }
    m_s[i] = a;
  }
  __syncthreads();

  int wave = tid >> 6;
  int lane = tid & 63;
  // hoisted LDS fragment of m (same for all rows this wave computes)
  float4 ma = ((const float4*)m_s)[lane];
  float4 mb = ((const float4*)m_s)[64 + lane];

#pragma unroll 4
  for (int rr = 0; rr < 16; ++rr) {
    int e = et * 64 + wave * 16 + rr;
    const float4* wrow = (const float4*)(W + (size_t)e * DD);
    float p = dot4(wrow[lane], ma) + dot4(wrow[64 + lane], mb);
#pragma unroll
    for (int m = 1; m <= 32; m <<= 1) p += __shfl_xor(p, m);
    if (lane == 0) out[(size_t)bk * DD + e] = p;
  }
}

// ---------------------------------------------------------------------------
// k5: out[b,s,:] = sum_k attn[b,s,k]*ws2[b,k,:]. 2048 blocks x 256 thr;
// thread owns float4 e-slot; 16B coalesced stores.
// ---------------------------------------------------------------------------
__global__ __launch_bounds__(256) void k5_gather(
    const float* __restrict__ attn, const float* __restrict__ ws2,
    float* __restrict__ out) {
  int tid = threadIdx.x;
  int b = blockIdx.x >> 9;           // 512 chunks per batch
  int sc = blockIdx.x & 511;
  size_t s0 = (size_t)sc * 16;
  int tr = tid >> 7;                 // 0/1: which of two token rows
  int e4 = tid & 127;                // float4 column slot

  float4 w[KK];
  const float* wb = ws2 + (size_t)b * KK * DD + e4 * 4;
#pragma unroll
  for (int k = 0; k < KK; ++k) w[k] = *(const float4*)(wb + (size_t)k * DD);

  size_t rowA = (size_t)b * SS + s0 + tr;
  const float* ar = attn + rowA * KK;
  float* orow = out + rowA * DD + e4 * 4;

#pragma unroll 2
  for (int i = 0; i < 8; ++i) {
    const float4* a4 = (const float4*)(ar + (size_t)2 * i * KK);
    float4 A = a4[0], Bv = a4[1], C = a4[2], Dv = a4[3], E = a4[4];
    float4 o = make_float4(0.f, 0.f, 0.f, 0.f);
#define ACC(av, kbase) \
    o.x += av * w[kbase].x; o.y += av * w[kbase].y; \
    o.z += av * w[kbase].z; o.w += av * w[kbase].w;
    ACC(A.x, 0)  ACC(A.y, 1)  ACC(A.z, 2)  ACC(A.w, 3)
    ACC(Bv.x, 4) ACC(Bv.y, 5) ACC(Bv.z, 6) ACC(Bv.w, 7)
    ACC(C.x, 8)  ACC(C.y, 9)  ACC(C.z, 10) ACC(C.w, 11)
    ACC(Dv.x, 12) ACC(Dv.y, 13) ACC(Dv.z, 14) ACC(Dv.w, 15)
    ACC(E.x, 16) ACC(E.y, 17) ACC(E.z, 18) ACC(E.w, 19)
#undef ACC
    *(float4*)(orow + (size_t)2 * i * DD) = o;
  }
}

// ---------------------------------------------------------------------------
extern "C" void kernel_launch(void* const* d_in, const int* in_sizes, int n_in,
                              void* d_out, int out_size, void* d_ws, size_t ws_size,
                              hipStream_t stream) {
  const float* x   = (const float*)d_in[0];
  const float* pos = (const float*)d_in[1];
  const float* ls  = (const float*)d_in[2];
  const float* am  = (const float*)d_in[3];
  const float* w_v = (const float*)d_in[4];
  const float* w_o = (const float*)d_in[5];
  float* out = (float*)d_out;

  float* ws     = (float*)d_ws;
  float* attn   = ws;                                 // B*S*K = 655360 f
  float* ws2    = attn + (size_t)BB * SS * KK;        // B*K*D = 40960 f
  float* ssb    = ws2 + (size_t)BB * KK * DD;         // 40960 f
  float* params = ssb + (size_t)BB * KK * DD;         // 64 f
  float* red8   = params + 64;                        // GG*BKD = 327680 f
  float* Mpart  = red8 + (size_t)GG * BKD;

  size_t head_f = (size_t)BB * SS * KK + 2 * (size_t)BB * KK * DD + 64 + (size_t)GG * BKD;
  int cpb = 128, tpc = 64;                            // 512 scatter blocks, Mpart 21 MB
  size_t need = (head_f + (size_t)BB * cpb * KK * DD) * sizeof(float);  // ~25.3 MB
  if (ws_size < need) { cpb = 64; tpc = 128; }                          // ~14.8 MB
  int cpg = cpb / GG;

  k0_params<<<KK, 64, 0, stream>>>(pos, ls, am, params);
  kA_attn<<<512, 256, 0, stream>>>(x, pos, params, attn);
  kB_scatter<<<dim3(cpb, BB), 256, 0, stream>>>(x, attn, Mpart, tpc);
  kC1_reduce<<<(GG * BKD) / 256, 256, 0, stream>>>(Mpart, red8, cpb, cpg);
  kP_gemv<<<dim3(BB * KK, 8), 256, 0, stream>>>(red8, w_v, ssb, 0);  // M -> ssb
  kP_gemv<<<dim3(BB * KK, 8), 256, 0, stream>>>(ssb, w_o, ws2, 1);   // ssb -> ws2
  k5_gather<<<2048, 256, 0, stream>>>(attn, ws2, out);
}

// Round 7
// 239.361 us; speedup vs baseline: 1.2153x; 1.0731x over previous
//
#include <hip/hip_runtime.h>
#include <hip/hip_bf16.h>

// Problem constants (reference: B,S,D,K = 4, 8192, 512, 20)
#define BB 4
#define SS 8192
#define DD 512
#define KK 20
#define KH 10                // splats per kA half-pass
#define GG 8                 // reduce groups
#define BKD (BB * KK * DD)   // 40960

__device__ __forceinline__ float dot4(float4 a, float4 b) {
  return a.x * b.x + a.y * b.y + a.z * b.z + a.w * b.w;
}

// ---------------------------------------------------------------------------
// k0: params[k]=||c_k||^2, params[K+k]=0.5/sigma^2, params[2K+k]=amp
// ---------------------------------------------------------------------------
__global__ void k0_params(const float* __restrict__ pos,
                          const float* __restrict__ log_scales,
                          const float* __restrict__ amps,
                          float* __restrict__ params) {
  int k = blockIdx.x;
  int lane = threadIdx.x;
  float acc = 0.f;
  for (int d = lane; d < DD; d += 64) { float p = pos[k * DD + d]; acc += p * p; }
#pragma unroll
  for (int off = 32; off > 0; off >>= 1) acc += __shfl_xor(acc, off);
  if (lane == 0) {
    params[k] = acc;
    float s = __expf(log_scales[k]);
    params[KK + k] = 0.5f / (s * s);
    params[2 * KK + k] = amps[k];
  }
}

// ---------------------------------------------------------------------------
// kA: UNNORMALIZED gauss, K split in two half-passes (blockIdx.y = kh).
// grid (512, 2) x 256 thr; 64 tokens/block; 16 lanes/token; 4 tokens/thread.
// LDS 23KB -> 6 blocks/CU cap; 1024 blocks -> ~4/CU -> ~50% occupancy.
// Writes g[b,s, kh*10 .. kh*10+9] and gsum[(b*S+s)*2 + kh] (partial sum).
// ---------------------------------------------------------------------------
__global__ __launch_bounds__(256) void kA_gauss(
    const float* __restrict__ x, const float* __restrict__ pos,
    const float* __restrict__ params, float* __restrict__ gbuf,
    float* __restrict__ gsum) {
  __shared__ float pos_s[KH * DD];   // 20 KB
  __shared__ float g_s[64 * KH];     // 2.5 KB
  __shared__ float prm_s[3 * KH];
  int tid = threadIdx.x;
  int kh = blockIdx.y;

  for (int i = tid; i < KH * DD / 4; i += 256)
    ((float4*)pos_s)[i] = ((const float4*)(pos + kh * KH * DD))[i];
  if (tid < KH) {
    prm_s[tid]          = params[kh * KH + tid];            // c2
    prm_s[KH + tid]     = params[KK + kh * KH + tid];       // alpha
    prm_s[2 * KH + tid] = params[2 * KK + kh * KH + tid];   // amp
  }
  __syncthreads();

  int b = blockIdx.x >> 7;           // 128 chunks/batch, 64 tokens each
  int c = blockIdx.x & 127;
  size_t row0 = (size_t)b * SS + (size_t)c * 64;
  int q = tid >> 4;                  // 0..15
  int dsub = tid & 15;

  const float* xq = x + (row0 + q) * DD;

  float acc[4][KH];
  float x2[4];
#pragma unroll
  for (int r = 0; r < 4; ++r) {
    x2[r] = 0.f;
#pragma unroll
    for (int k = 0; k < KH; ++k) acc[r][k] = 0.f;
  }

#pragma unroll 2
  for (int j = 0; j < 8; ++j) {
    int d0 = j * 64 + dsub * 4;
    float4 xv[4];
#pragma unroll
    for (int r = 0; r < 4; ++r) xv[r] = *(const float4*)(xq + (size_t)(r * 16) * DD + d0);
#pragma unroll
    for (int r = 0; r < 4; ++r) x2[r] += dot4(xv[r], xv[r]);
#pragma unroll
    for (int k = 0; k < KH; ++k) {
      float4 p = *(const float4*)(pos_s + k * DD + d0);
#pragma unroll
      for (int r = 0; r < 4; ++r) acc[r][k] += dot4(xv[r], p);
    }
  }

#pragma unroll
  for (int r = 0; r < 4; ++r) {
#pragma unroll
    for (int m = 1; m <= 8; m <<= 1) x2[r] += __shfl_xor(x2[r], m);
#pragma unroll
    for (int k = 0; k < KH; ++k) {
#pragma unroll
      for (int m = 1; m <= 8; m <<= 1) acc[r][k] += __shfl_xor(acc[r][k], m);
    }
  }

  if (dsub == 0) {
#pragma unroll
    for (int r = 0; r < 4; ++r) {
      int tok = q + r * 16;
      float sum = 0.f;
#pragma unroll
      for (int k = 0; k < KH; ++k) {
        float d2 = fmaxf(x2[r] - 2.f * acc[r][k] + prm_s[k], 0.f);
        float g = prm_s[2 * KH + k] * __expf(-prm_s[KH + k] * d2);
        g_s[tok * KH + k] = g;
        sum += g;
      }
      gsum[(row0 + tok) * 2 + kh] = sum;
    }
  }
  __syncthreads();

  // coalesced-ish copy of the half-rows to global: g[row][kh*10 + kl]
  for (int i = tid; i < 64 * KH; i += 256) {
    int tok = i / KH, kl = i - tok * KH;
    gbuf[(row0 + tok) * KK + kh * KH + kl] = g_s[i];
  }
}

// ---------------------------------------------------------------------------
// kB: Mpart[b,c,k,d] = sum_{s in chunk} attn[s,k]*x[s,d], attn = g*inv.
// inv folded into x (2 mults/token). grid (cpb, BB) x 256 thr.
// ---------------------------------------------------------------------------
__global__ __launch_bounds__(256) void kB_scatter(
    const float* __restrict__ x, const float* __restrict__ gbuf,
    const float* __restrict__ gsum, float* __restrict__ Mpart, int tpc) {
  int t = threadIdx.x;
  int c = blockIdx.x;
  int b = blockIdx.y;
  int cpb = gridDim.x;
  size_t row0 = (size_t)b * SS + (size_t)c * tpc;

  float2 Ml[KK];
#pragma unroll
  for (int k = 0; k < KK; ++k) Ml[k] = make_float2(0.f, 0.f);

  const float* xb = x + row0 * DD + 2 * t;
  const float* ab = gbuf + row0 * KK;
  const float* sb = gsum + row0 * 2;
  for (int s = 0; s < tpc; ++s) {
    float2 sv = *(const float2*)(sb + 2 * s);
    float inv = 1.f / (sv.x + sv.y + 1e-8f);
    float2 xv = *(const float2*)(xb + (size_t)s * DD);
    xv.x *= inv; xv.y *= inv;
    const float4* ar4 = (const float4*)(ab + s * KK);
#pragma unroll
    for (int kk = 0; kk < KK / 4; ++kk) {
      float4 a4 = ar4[kk];
      Ml[4 * kk + 0].x += a4.x * xv.x; Ml[4 * kk + 0].y += a4.x * xv.y;
      Ml[4 * kk + 1].x += a4.y * xv.x; Ml[4 * kk + 1].y += a4.y * xv.y;
      Ml[4 * kk + 2].x += a4.z * xv.x; Ml[4 * kk + 2].y += a4.z * xv.y;
      Ml[4 * kk + 3].x += a4.w * xv.x; Ml[4 * kk + 3].y += a4.w * xv.y;
    }
  }
  float* mp = Mpart + ((size_t)b * cpb + c) * KK * DD + 2 * t;
#pragma unroll
  for (int k = 0; k < KK; ++k) *(float2*)(mp + (size_t)k * DD) = Ml[k];
}

// ---------------------------------------------------------------------------
// kC1: parallel partial reduce Mpart -> red8[GG][B,K,D]. Coalesced.
// ---------------------------------------------------------------------------
__global__ __launch_bounds__(256) void kC1_reduce(
    const float* __restrict__ Mpart, float* __restrict__ red8,
    int cpb, int cpg) {
  int idx = blockIdx.x * 256 + threadIdx.x;   // 0 .. GG*BKD-1
  int g = idx / BKD;
  int rem = idx - g * BKD;
  int b = rem / (KK * DD);
  int kd = rem - b * (KK * DD);
  const float* p = Mpart + ((size_t)b * cpb + (size_t)g * cpg) * KK * DD + kd;
  float acc = 0.f;
#pragma unroll 8
  for (int c = 0; c < cpg; ++c) acc += p[(size_t)c * KK * DD];
  red8[idx] = acc;
}

// ---------------------------------------------------------------------------
// kP: coalesced GEMV tile: out[bk][e] = sum_d in[bk][d] * W[e][d].
// grid (80, 8) x 256 thr; wave-per-row, 64 consecutive float4 per instr.
// mode 0: m = sum_g red8[g][bk][:]; mode 1: m = in[bk][:].
// ---------------------------------------------------------------------------
__global__ __launch_bounds__(256) void kP_gemv(
    const float* __restrict__ in, const float* __restrict__ W,
    float* __restrict__ out, int mode) {
  __shared__ float m_s[DD];
  int tid = threadIdx.x;
  int bk = blockIdx.x;
  int et = blockIdx.y;

  for (int i = tid; i < DD; i += 256) {
    float a;
    if (mode == 0) {
      const float* p = in + (size_t)bk * DD + i;
      a = 0.f;
#pragma unroll
      for (int g = 0; g < GG; ++g) a += p[(size_t)g * BKD];
    } else {
      a = in[(size_t)bk * DD + i];
    }
    m_s[i] = a;
  }
  __syncthreads();

  int wave = tid >> 6;
  int lane = tid & 63;
  float4 ma = ((const float4*)m_s)[lane];
  float4 mb = ((const float4*)m_s)[64 + lane];

#pragma unroll 4
  for (int rr = 0; rr < 16; ++rr) {
    int e = et * 64 + wave * 16 + rr;
    const float4* wrow = (const float4*)(W + (size_t)e * DD);
    float p = dot4(wrow[lane], ma) + dot4(wrow[64 + lane], mb);
#pragma unroll
    for (int m = 1; m <= 32; m <<= 1) p += __shfl_xor(p, m);
    if (lane == 0) out[(size_t)bk * DD + e] = p;
  }
}

// ---------------------------------------------------------------------------
// k5: out[b,s,:] = inv[s] * sum_k g[b,s,k]*ws2[b,k,:]. 2048 blocks x 256 thr;
// thread owns float4 e-slot; 16B coalesced stores.
// ---------------------------------------------------------------------------
__global__ __launch_bounds__(256) void k5_gather(
    const float* __restrict__ gbuf, const float* __restrict__ gsum,
    const float* __restrict__ ws2, float* __restrict__ out) {
  int tid = threadIdx.x;
  int b = blockIdx.x >> 9;           // 512 chunks per batch
  int sc = blockIdx.x & 511;
  size_t s0 = (size_t)sc * 16;
  int tr = tid >> 7;                 // 0/1: which of two token rows
  int e4 = tid & 127;                // float4 column slot

  float4 w[KK];
  const float* wb = ws2 + (size_t)b * KK * DD + e4 * 4;
#pragma unroll
  for (int k = 0; k < KK; ++k) w[k] = *(const float4*)(wb + (size_t)k * DD);

  size_t rowA = (size_t)b * SS + s0 + tr;
  const float* ar = gbuf + rowA * KK;
  const float* sr = gsum + rowA * 2;
  float* orow = out + rowA * DD + e4 * 4;

#pragma unroll 2
  for (int i = 0; i < 8; ++i) {
    const float4* a4 = (const float4*)(ar + (size_t)2 * i * KK);
    float2 sv = *(const float2*)(sr + (size_t)4 * i);
    float inv = 1.f / (sv.x + sv.y + 1e-8f);
    float4 A = a4[0], Bv = a4[1], C = a4[2], Dv = a4[3], E = a4[4];
    float4 o = make_float4(0.f, 0.f, 0.f, 0.f);
#define ACC(av, kbase) \
    o.x += av * w[kbase].x; o.y += av * w[kbase].y; \
    o.z += av * w[kbase].z; o.w += av * w[kbase].w;
    ACC(A.x, 0)  ACC(A.y, 1)  ACC(A.z, 2)  ACC(A.w, 3)
    ACC(Bv.x, 4) ACC(Bv.y, 5) ACC(Bv.z, 6) ACC(Bv.w, 7)
    ACC(C.x, 8)  ACC(C.y, 9)  ACC(C.z, 10) ACC(C.w, 11)
    ACC(Dv.x, 12) ACC(Dv.y, 13) ACC(Dv.z, 14) ACC(Dv.w, 15)
    ACC(E.x, 16) ACC(E.y, 17) ACC(E.z, 18) ACC(E.w, 19)
#undef ACC
    o.x *= inv; o.y *= inv; o.z *= inv; o.w *= inv;
    *(float4*)(orow + (size_t)2 * i * DD) = o;
  }
}

// ---------------------------------------------------------------------------
extern "C" void kernel_launch(void* const* d_in, const int* in_sizes, int n_in,
                              void* d_out, int out_size, void* d_ws, size_t ws_size,
                              hipStream_t stream) {
  const float* x   = (const float*)d_in[0];
  const float* pos = (const float*)d_in[1];
  const float* ls  = (const float*)d_in[2];
  const float* am  = (const float*)d_in[3];
  const float* w_v = (const float*)d_in[4];
  const float* w_o = (const float*)d_in[5];
  float* out = (float*)d_out;

  float* ws     = (float*)d_ws;
  float* gbuf   = ws;                                 // B*S*K = 655360 f
  float* gsum   = gbuf + (size_t)BB * SS * KK;        // B*S*2 = 65536 f
  float* ws2    = gsum + (size_t)BB * SS * 2;         // 40960 f
  float* ssb    = ws2 + (size_t)BB * KK * DD;         // 40960 f
  float* params = ssb + (size_t)BB * KK * DD;         // 64 f
  float* red8   = params + 64;                        // GG*BKD = 327680 f
  float* Mpart  = red8 + (size_t)GG * BKD;

  size_t head_f = (size_t)BB * SS * KK + (size_t)BB * SS * 2 +
                  2 * (size_t)BB * KK * DD + 64 + (size_t)GG * BKD;
  int cpb = 256;                                      // 1024 scatter blocks
  size_t need = (head_f + (size_t)BB * cpb * KK * DD) * sizeof(float);  // ~46.5 MB
  if (ws_size < need) { cpb = 128; need = (head_f + (size_t)BB * cpb * KK * DD) * sizeof(float); }
  if (ws_size < need) { cpb = 64; }
  int tpc = SS / cpb;
  int cpg = cpb / GG;

  k0_params<<<KK, 64, 0, stream>>>(pos, ls, am, params);
  kA_gauss<<<dim3(512, 2), 256, 0, stream>>>(x, pos, params, gbuf, gsum);
  kB_scatter<<<dim3(cpb, BB), 256, 0, stream>>>(x, gbuf, gsum, Mpart, tpc);
  kC1_reduce<<<(GG * BKD) / 256, 256, 0, stream>>>(Mpart, red8, cpb, cpg);
  kP_gemv<<<dim3(BB * KK, 8), 256, 0, stream>>>(red8, w_v, ssb, 0);  // M -> ssb
  kP_gemv<<<dim3(BB * KK, 8), 256, 0, stream>>>(ssb, w_o, ws2, 1);   // ssb -> ws2
  k5_gather<<<2048, 256, 0, stream>>>(gbuf, gsum, ws2, out);
}